// Round 1
// baseline (330.905 us; speedup 1.0000x reference)
//
#include <hip/hip_runtime.h>
#include <stdint.h>

typedef unsigned int u32;
typedef unsigned long long u64;

#define NTOT 21824   // 128*128 + 64*64 + 32*32 + 16*16 + 8*8
#define NBATCH 16
#define TOPN 1000
#define MAXOBJ 100
#define CAP 2048     // gather capacity (>= TOPN + pivot ties)

// -------------------------------------------------------------------------
// Stage 1: decode.  One thread per (batch, location).
// score = sqrt(max_c cls * ctr); class = argmax (first max); box = trunc(ltrb)
// pos is recomputed exactly: (w+0.5)*s is exact fp32 (s power of two).
// -------------------------------------------------------------------------
__global__ __launch_bounds__(256) void decode_kernel(
    const float* __restrict__ cls0, const float* __restrict__ cls1,
    const float* __restrict__ cls2, const float* __restrict__ cls3,
    const float* __restrict__ cls4,
    const float* __restrict__ reg0, const float* __restrict__ reg1,
    const float* __restrict__ reg2, const float* __restrict__ reg3,
    const float* __restrict__ reg4,
    const float* __restrict__ ctr0, const float* __restrict__ ctr1,
    const float* __restrict__ ctr2, const float* __restrict__ ctr3,
    const float* __restrict__ ctr4,
    u32* __restrict__ keys, int* __restrict__ clsidx, float4* __restrict__ boxes)
{
    int loc = blockIdx.x * 256 + threadIdx.x;
    int b = blockIdx.y;
    if (loc >= NTOT) return;
    const float *cp, *rp, *tp;
    int li, wsh; float st;
    if (loc < 16384)      { li = loc;         wsh = 7; st = 8.f;   size_t o = (size_t)b*16384 + li; cp = cls0 + o*80; rp = reg0 + o*4; tp = ctr0 + o; }
    else if (loc < 20480) { li = loc - 16384; wsh = 6; st = 16.f;  size_t o = (size_t)b*4096  + li; cp = cls1 + o*80; rp = reg1 + o*4; tp = ctr1 + o; }
    else if (loc < 21504) { li = loc - 20480; wsh = 5; st = 32.f;  size_t o = (size_t)b*1024  + li; cp = cls2 + o*80; rp = reg2 + o*4; tp = ctr2 + o; }
    else if (loc < 21760) { li = loc - 21504; wsh = 4; st = 64.f;  size_t o = (size_t)b*256   + li; cp = cls3 + o*80; rp = reg3 + o*4; tp = ctr3 + o; }
    else                  { li = loc - 21760; wsh = 3; st = 128.f; size_t o = (size_t)b*64    + li; cp = cls4 + o*80; rp = reg4 + o*4; tp = ctr4 + o; }
    int wx = li & ((1 << wsh) - 1);
    int hy = li >> wsh;
    float px = ((float)wx + 0.5f) * st;
    float py = ((float)hy + 0.5f) * st;

    const float4* c4 = (const float4*)cp;
    float maxv = -1.0f; int arg = 0;
#pragma unroll
    for (int q = 0; q < 20; ++q) {
        float4 v = c4[q];
        if (v.x > maxv) { maxv = v.x; arg = 4*q;     }
        if (v.y > maxv) { maxv = v.y; arg = 4*q + 1; }
        if (v.z > maxv) { maxv = v.z; arg = 4*q + 2; }
        if (v.w > maxv) { maxv = v.w; arg = 4*q + 3; }
    }
    float ctr = *tp;
    float score = sqrtf(maxv * ctr);           // correctly-rounded fp32 sqrt (default HIP)
    float4 r = *(const float4*)rp;
    float4 bx;
    bx.x = truncf(px - r.x); bx.y = truncf(py - r.y);
    bx.z = truncf(px + r.z); bx.w = truncf(py + r.w);
    size_t o = (size_t)b * NTOT + loc;
    // monotone key for positive floats; 0 == invalid (score <= MIN_SCORE)
    keys[o] = (score > 0.05f) ? (__float_as_uint(score) | 0x80000000u) : 0u;
    clsidx[o] = arg;
    boxes[o] = bx;
}

// -------------------------------------------------------------------------
// Stage 2: per-batch exact top-1000 (lax.top_k semantics: desc score, ties
// by lower index).  3-pass radix select (exact 32-bit pivot) + gather +
// 2048-elem bitonic sort of (key<<32 | ~loc) in LDS.
// -------------------------------------------------------------------------
__global__ __launch_bounds__(1024) void select_kernel(
    const u32* __restrict__ keys, const int* __restrict__ clsidx,
    const float4* __restrict__ boxes,
    float* __restrict__ tscore, float* __restrict__ tcls, float4* __restrict__ tbox)
{
    __shared__ u32 hist[2048];
    __shared__ u64 skey[CAP];
    __shared__ u32 s_prefix, s_above, s_target, s_gcnt;
    __shared__ int s_t;
    int b = blockIdx.x;
    int tid = threadIdx.x;
    const u32* kb = keys + (size_t)b * NTOT;

    if (tid == 0) { s_prefix = 0; s_above = 0; s_target = TOPN; }
    const int shifts[3] = {21, 10, 0};
    const int nbits[3]  = {11, 11, 10};
    for (int p = 0; p < 3; ++p) {
        hist[tid] = 0; hist[tid + 1024] = 0;
        if (tid == 0) s_t = -1;
        __syncthreads();
        u32 pre = s_prefix;
        u32 tgt = s_target;
        if (tgt > 0) {
            for (int loc = tid; loc < NTOT; loc += 1024) {
                u32 k = kb[loc];
                if (!k) continue;
                bool ok = (p == 0) || ((k >> (shifts[p] + nbits[p])) == pre);
                if (ok) atomicAdd(&hist[(k >> shifts[p]) & ((1u << nbits[p]) - 1)], 1u);
            }
        }
        __syncthreads();
        // parallel suffix-sum over 2048 bins (Hillis-Steele, in place)
        for (int off = 1; off < 2048; off <<= 1) {
            u32 v0 = hist[tid], v1 = hist[tid + 1024];
            u32 a0 = (tid + off < 2048) ? hist[tid + off] : 0;
            u32 a1 = (tid + 1024 + off < 2048) ? hist[tid + 1024 + off] : 0;
            __syncthreads();
            hist[tid] = v0 + a0; hist[tid + 1024] = v1 + a1;
            __syncthreads();
        }
        if (p == 0 && tid == 0) s_target = (hist[0] < TOPN) ? hist[0] : TOPN;
        __syncthreads();
        tgt = s_target;
        if (tgt > 0) {
            u32 need = tgt - s_above;   // >= 1 by invariant
            if (hist[tid] >= need) atomicMax(&s_t, tid);
            if (hist[tid + 1024] >= need) atomicMax(&s_t, tid + 1024);
            __syncthreads();
            if (tid == 0) {
                int t = s_t;
                u32 above = (t + 1 < 2048) ? hist[t + 1] : 0;
                s_above += above;
                s_prefix = (s_prefix << nbits[p]) | (u32)t;
            }
        }
        __syncthreads();
    }

    // gather all keys >= exact pivot, pad to CAP with zeros
    skey[tid] = 0; skey[tid + 1024] = 0;
    if (tid == 0) s_gcnt = 0;
    __syncthreads();
    u32 P = s_prefix;
    u32 tgt = s_target;
    if (tgt > 0) {
        for (int loc = tid; loc < NTOT; loc += 1024) {
            u32 k = kb[loc];
            if (k && k >= P) {
                u32 pos = atomicAdd(&s_gcnt, 1u);
                if (pos < CAP) skey[pos] = ((u64)k << 32) | (u32)(~loc);
            }
        }
    }
    __syncthreads();
    // bitonic sort, descending (score desc, then index asc via ~loc)
    for (u32 kk = 2; kk <= CAP; kk <<= 1) {
        for (u32 j = kk >> 1; j > 0; j >>= 1) {
            __syncthreads();
#pragma unroll
            for (int t2 = 0; t2 < 2; ++t2) {
                int l = tid + t2 * 1024;
                int pq = l ^ (int)j;
                if (pq > l) {
                    u64 a = skey[l], c = skey[pq];
                    bool sw = ((l & kk) == 0) ? (a < c) : (a > c);
                    if (sw) { skey[l] = c; skey[pq] = a; }
                }
            }
        }
    }
    __syncthreads();
    if (tid < TOPN) {
        u64 e = skey[tid];
        u32 k = (u32)(e >> 32);
        size_t o = (size_t)b * TOPN + tid;
        if (k) {
            u32 loc = ~(u32)(e & 0xFFFFFFFFull);
            float sc = __uint_as_float(k & 0x7FFFFFFFu);
            size_t src = (size_t)b * NTOT + loc;
            tscore[o] = sc;
            tcls[o]   = (float)clsidx[src];
            tbox[o]   = boxes[src];
        } else {
            tscore[o] = -1.0f;
            tcls[o]   = -1.0f;
            tbox[o]   = make_float4(0.f, 0.f, 0.f, 0.f);
        }
    }
}

// -------------------------------------------------------------------------
// Stage 3: suppression-bit matrix.  One wave per (batch,row); 16 ballots.
// bit(i,j) = (j > i) && IoU(i,j) >= 0.6   (exact fp32, matches reference)
// -------------------------------------------------------------------------
__global__ __launch_bounds__(64) void iou_kernel(
    const float4* __restrict__ tbox, u64* __restrict__ sup)
{
    int i = blockIdx.x, b = blockIdx.y, lane = threadIdx.x;
    float4 bi = tbox[(size_t)b * TOPN + i];
    float areai = fmaxf((bi.z - bi.x) * (bi.w - bi.y), 0.0001f);
    u64* row = sup + ((size_t)b * TOPN + i) * 16;
#pragma unroll
    for (int w = 0; w < 16; ++w) {
        int col = w * 64 + lane;
        bool bit = false;
        if (col < TOPN) {
            float4 bj = tbox[(size_t)b * TOPN + col];
            float areaj = fmaxf((bj.z - bj.x) * (bj.w - bj.y), 0.0001f);
            float tlx = fmaxf(bi.x, bj.x), tly = fmaxf(bi.y, bj.y);
            float brx = fminf(bi.z, bj.z), bry = fminf(bi.w, bj.w);
            float ow = fmaxf(brx - tlx, 0.f), oh = fmaxf(bry - tly, 0.f);
            float inter = ow * oh;
            float uni = fmaxf(areai + areaj - inter, 0.0001f);
            bit = (col > i) && (inter / uni >= 0.6f);
        }
        u64 m = __ballot(bit);
        if (lane == 0) row[w] = m;
    }
}

// -------------------------------------------------------------------------
// Stage 4: greedy serial scan (exact reference semantics) + compaction +
// output.  Wave 0 holds the 16-word removed mask in lanes 0..15, pre-seeded
// with ~valid so the loop chain is bit-test -> conditional OR only.
// -------------------------------------------------------------------------
__global__ __launch_bounds__(1024) void finalize_kernel(
    const float* __restrict__ tscore, const float* __restrict__ tcls,
    const float4* __restrict__ tbox, const u64* __restrict__ sup,
    float* __restrict__ out)
{
    __shared__ u64 mat[256 * 16];     // 32 KB chunk of the bit matrix
    __shared__ u32 validsh[TOPN];
    __shared__ u64 removed_sh[16];
    __shared__ u32 scanbuf[1024];
    int b = blockIdx.x, tid = threadIdx.x;
    int wave = tid >> 6, lane = tid & 63;

    for (int i = tid; i < TOPN; i += 1024)
        validsh[i] = (tscore[(size_t)b * TOPN + i] > 0.05f) ? 1u : 0u;
    __syncthreads();

    u64 my = 0;
    if (wave == 0) {
        // seed removed with ~valid: then "active" == !removed_bit
#pragma unroll
        for (int w2 = 0; w2 < 16; ++w2) {
            int i = w2 * 64 + lane;
            bool v = (i < TOPN) ? (validsh[i] != 0) : false;
            u64 m = __ballot(v);
            if (lane == w2) my = ~m;
        }
    }
    const u64* supb = sup + (size_t)b * TOPN * 16;
    for (int chunk = 0; chunk < 4; ++chunk) {
        int r0 = chunk * 256;
        int rows = (TOPN - r0 < 256) ? (TOPN - r0) : 256;
        __syncthreads();                       // scan of previous chunk done
        for (int idx = tid; idx < rows * 16; idx += 1024)
            mat[idx] = supb[(size_t)r0 * 16 + idx];
        __syncthreads();
        if (wave == 0) {
            int lw = lane & 15;
            for (int sub = 0; sub < rows; sub += 64) {
                int w2 = (r0 + sub) >> 6;      // word containing these 64 rows
                u64 cur = __shfl(my, w2);      // all lanes mirror word w2
                int nsub = (rows - sub < 64) ? (rows - sub) : 64;
                for (int u = 0; u < nsub; ++u) {
                    u64 rowme = mat[(sub + u) * 16 + lw];
                    u64 roww  = mat[(sub + u) * 16 + w2];
                    if (!((cur >> u) & 1ull)) { cur |= roww; my |= rowme; }
                }
            }
        }
    }
    if (wave == 0 && lane < 16) removed_sh[lane] = my;
    __syncthreads();

    u32 keep = 0;
    if (tid < TOPN)
        keep = (validsh[tid] && !((removed_sh[tid >> 6] >> (tid & 63)) & 1ull)) ? 1u : 0u;
    scanbuf[tid] = keep;
    __syncthreads();
    for (int off = 1; off < 1024; off <<= 1) {
        u32 add = (tid >= off) ? scanbuf[tid - off] : 0;
        __syncthreads();
        scanbuf[tid] += add;
        __syncthreads();
    }
    int rank = (int)scanbuf[tid] - 1;

    float* out_s = out;
    float* out_c = out + NBATCH * MAXOBJ;
    float* out_b = out + 2 * NBATCH * MAXOBJ;
    if (tid < MAXOBJ)     { out_s[b * MAXOBJ + tid] = -1.f; out_c[b * MAXOBJ + tid] = -1.f; }
    if (tid < MAXOBJ * 4) out_b[b * MAXOBJ * 4 + tid] = 0.f;
    __syncthreads();
    if (tid < TOPN && keep && rank < MAXOBJ) {
        size_t o = (size_t)b * TOPN + tid;
        out_s[b * MAXOBJ + rank] = tscore[o];
        out_c[b * MAXOBJ + rank] = tcls[o];
        ((float4*)out_b)[b * MAXOBJ + rank] = tbox[o];
    }
}

// -------------------------------------------------------------------------
// Workspace layout (bytes):                            requires ~10.32 MB
//   keys   u32 [16][21824]          @ 0          (1,396,736)
//   clsidx i32 [16][21824]          @ 1,396,736  (1,396,736)
//   boxes  f4  [16][21824]          @ 2,793,472  (5,586,944)
//   tscore f32 [16][1000]           @ 8,380,416  (64,000)
//   tcls   f32 [16][1000]           @ 8,444,416  (64,000)
//   tbox   f4  [16][1000]           @ 8,508,416  (256,000)
//   sup    u64 [16][1000][16]       @ 8,764,416  (2,048,000) -> end 10,812,416
// -------------------------------------------------------------------------
extern "C" void kernel_launch(void* const* d_in, const int* in_sizes, int n_in,
                              void* d_out, int out_size, void* d_ws, size_t ws_size,
                              hipStream_t stream) {
    (void)in_sizes; (void)n_in; (void)out_size; (void)ws_size;
    const float* cls[5]; const float* reg[5]; const float* ctr[5];
    for (int l = 0; l < 5; ++l) {
        cls[l] = (const float*)d_in[4 * l + 0];
        reg[l] = (const float*)d_in[4 * l + 1];
        ctr[l] = (const float*)d_in[4 * l + 2];
        // d_in[4*l+3] = pos, recomputed exactly on-device
    }
    char* w = (char*)d_ws;
    u32*    keys   = (u32*)(w + 0);
    int*    clsidx = (int*)(w + 1396736);
    float4* boxes  = (float4*)(w + 2793472);
    float*  tscore = (float*)(w + 8380416);
    float*  tcls   = (float*)(w + 8444416);
    float4* tbox   = (float4*)(w + 8508416);
    u64*    sup    = (u64*)(w + 8764416);

    decode_kernel<<<dim3((NTOT + 255) / 256, NBATCH), 256, 0, stream>>>(
        cls[0], cls[1], cls[2], cls[3], cls[4],
        reg[0], reg[1], reg[2], reg[3], reg[4],
        ctr[0], ctr[1], ctr[2], ctr[3], ctr[4],
        keys, clsidx, boxes);
    select_kernel<<<NBATCH, 1024, 0, stream>>>(keys, clsidx, boxes, tscore, tcls, tbox);
    iou_kernel<<<dim3(TOPN, NBATCH), 64, 0, stream>>>(tbox, sup);
    finalize_kernel<<<NBATCH, 1024, 0, stream>>>(tscore, tcls, tbox, sup, (float*)d_out);
}

// Round 2
// 305.357 us; speedup vs baseline: 1.0837x; 1.0837x over previous
//
#include <hip/hip_runtime.h>
#include <stdint.h>

typedef unsigned int u32;
typedef unsigned long long u64;

#define NTOT 21824   // 128*128 + 64*64 + 32*32 + 16*16 + 8*8
#define NBATCH 16
#define TOPN 1000
#define MAXOBJ 100
#define CAP 2048     // gather capacity (>= TOPN + pivot ties)

// -------------------------------------------------------------------------
// Stage 1: decode.  One thread per (batch, location).
// -------------------------------------------------------------------------
__global__ __launch_bounds__(256) void decode_kernel(
    const float* __restrict__ cls0, const float* __restrict__ cls1,
    const float* __restrict__ cls2, const float* __restrict__ cls3,
    const float* __restrict__ cls4,
    const float* __restrict__ reg0, const float* __restrict__ reg1,
    const float* __restrict__ reg2, const float* __restrict__ reg3,
    const float* __restrict__ reg4,
    const float* __restrict__ ctr0, const float* __restrict__ ctr1,
    const float* __restrict__ ctr2, const float* __restrict__ ctr3,
    const float* __restrict__ ctr4,
    u32* __restrict__ keys, int* __restrict__ clsidx, float4* __restrict__ boxes)
{
    int loc = blockIdx.x * 256 + threadIdx.x;
    int b = blockIdx.y;
    if (loc >= NTOT) return;
    const float *cp, *rp, *tp;
    int li, wsh; float st;
    if (loc < 16384)      { li = loc;         wsh = 7; st = 8.f;   size_t o = (size_t)b*16384 + li; cp = cls0 + o*80; rp = reg0 + o*4; tp = ctr0 + o; }
    else if (loc < 20480) { li = loc - 16384; wsh = 6; st = 16.f;  size_t o = (size_t)b*4096  + li; cp = cls1 + o*80; rp = reg1 + o*4; tp = ctr1 + o; }
    else if (loc < 21504) { li = loc - 20480; wsh = 5; st = 32.f;  size_t o = (size_t)b*1024  + li; cp = cls2 + o*80; rp = reg2 + o*4; tp = ctr2 + o; }
    else if (loc < 21760) { li = loc - 21504; wsh = 4; st = 64.f;  size_t o = (size_t)b*256   + li; cp = cls3 + o*80; rp = reg3 + o*4; tp = ctr3 + o; }
    else                  { li = loc - 21760; wsh = 3; st = 128.f; size_t o = (size_t)b*64    + li; cp = cls4 + o*80; rp = reg4 + o*4; tp = ctr4 + o; }
    int wx = li & ((1 << wsh) - 1);
    int hy = li >> wsh;
    float px = ((float)wx + 0.5f) * st;
    float py = ((float)hy + 0.5f) * st;

    const float4* c4 = (const float4*)cp;
    float maxv = -1.0f; int arg = 0;
#pragma unroll
    for (int q = 0; q < 20; ++q) {
        float4 v = c4[q];
        if (v.x > maxv) { maxv = v.x; arg = 4*q;     }
        if (v.y > maxv) { maxv = v.y; arg = 4*q + 1; }
        if (v.z > maxv) { maxv = v.z; arg = 4*q + 2; }
        if (v.w > maxv) { maxv = v.w; arg = 4*q + 3; }
    }
    float ctr = *tp;
    float score = sqrtf(maxv * ctr);           // correctly-rounded fp32 sqrt (default HIP)
    float4 r = *(const float4*)rp;
    float4 bx;
    bx.x = truncf(px - r.x); bx.y = truncf(py - r.y);
    bx.z = truncf(px + r.z); bx.w = truncf(py + r.w);
    size_t o = (size_t)b * NTOT + loc;
    keys[o] = (score > 0.05f) ? (__float_as_uint(score) | 0x80000000u) : 0u;
    clsidx[o] = arg;
    boxes[o] = bx;
}

// -------------------------------------------------------------------------
// Stage 2: per-batch exact top-1000 (lax.top_k semantics).
// -------------------------------------------------------------------------
__global__ __launch_bounds__(1024) void select_kernel(
    const u32* __restrict__ keys, const int* __restrict__ clsidx,
    const float4* __restrict__ boxes,
    float* __restrict__ tscore, float* __restrict__ tcls, float4* __restrict__ tbox)
{
    __shared__ u32 hist[2048];
    __shared__ u64 skey[CAP];
    __shared__ u32 s_prefix, s_above, s_target, s_gcnt;
    __shared__ int s_t;
    int b = blockIdx.x;
    int tid = threadIdx.x;
    const u32* kb = keys + (size_t)b * NTOT;

    if (tid == 0) { s_prefix = 0; s_above = 0; s_target = TOPN; }
    const int shifts[3] = {21, 10, 0};
    const int nbits[3]  = {11, 11, 10};
    for (int p = 0; p < 3; ++p) {
        hist[tid] = 0; hist[tid + 1024] = 0;
        if (tid == 0) s_t = -1;
        __syncthreads();
        u32 pre = s_prefix;
        u32 tgt = s_target;
        if (tgt > 0) {
            for (int loc = tid; loc < NTOT; loc += 1024) {
                u32 k = kb[loc];
                if (!k) continue;
                bool ok = (p == 0) || ((k >> (shifts[p] + nbits[p])) == pre);
                if (ok) atomicAdd(&hist[(k >> shifts[p]) & ((1u << nbits[p]) - 1)], 1u);
            }
        }
        __syncthreads();
        for (int off = 1; off < 2048; off <<= 1) {
            u32 v0 = hist[tid], v1 = hist[tid + 1024];
            u32 a0 = (tid + off < 2048) ? hist[tid + off] : 0;
            u32 a1 = (tid + 1024 + off < 2048) ? hist[tid + 1024 + off] : 0;
            __syncthreads();
            hist[tid] = v0 + a0; hist[tid + 1024] = v1 + a1;
            __syncthreads();
        }
        if (p == 0 && tid == 0) s_target = (hist[0] < TOPN) ? hist[0] : TOPN;
        __syncthreads();
        tgt = s_target;
        if (tgt > 0) {
            u32 need = tgt - s_above;
            if (hist[tid] >= need) atomicMax(&s_t, tid);
            if (hist[tid + 1024] >= need) atomicMax(&s_t, tid + 1024);
            __syncthreads();
            if (tid == 0) {
                int t = s_t;
                u32 above = (t + 1 < 2048) ? hist[t + 1] : 0;
                s_above += above;
                s_prefix = (s_prefix << nbits[p]) | (u32)t;
            }
        }
        __syncthreads();
    }

    skey[tid] = 0; skey[tid + 1024] = 0;
    if (tid == 0) s_gcnt = 0;
    __syncthreads();
    u32 P = s_prefix;
    u32 tgt = s_target;
    if (tgt > 0) {
        for (int loc = tid; loc < NTOT; loc += 1024) {
            u32 k = kb[loc];
            if (k && k >= P) {
                u32 pos = atomicAdd(&s_gcnt, 1u);
                if (pos < CAP) skey[pos] = ((u64)k << 32) | (u32)(~loc);
            }
        }
    }
    __syncthreads();
    for (u32 kk = 2; kk <= CAP; kk <<= 1) {
        for (u32 j = kk >> 1; j > 0; j >>= 1) {
            __syncthreads();
#pragma unroll
            for (int t2 = 0; t2 < 2; ++t2) {
                int l = tid + t2 * 1024;
                int pq = l ^ (int)j;
                if (pq > l) {
                    u64 a = skey[l], c = skey[pq];
                    bool sw = ((l & kk) == 0) ? (a < c) : (a > c);
                    if (sw) { skey[l] = c; skey[pq] = a; }
                }
            }
        }
    }
    __syncthreads();
    if (tid < TOPN) {
        u64 e = skey[tid];
        u32 k = (u32)(e >> 32);
        size_t o = (size_t)b * TOPN + tid;
        if (k) {
            u32 loc = ~(u32)(e & 0xFFFFFFFFull);
            float sc = __uint_as_float(k & 0x7FFFFFFFu);
            size_t src = (size_t)b * NTOT + loc;
            tscore[o] = sc;
            tcls[o]   = (float)clsidx[src];
            tbox[o]   = boxes[src];
        } else {
            tscore[o] = -1.0f;
            tcls[o]   = -1.0f;
            tbox[o]   = make_float4(0.f, 0.f, 0.f, 0.f);
        }
    }
}

// -------------------------------------------------------------------------
// Stage 3: suppression-bit matrix.
// -------------------------------------------------------------------------
__global__ __launch_bounds__(64) void iou_kernel(
    const float4* __restrict__ tbox, u64* __restrict__ sup)
{
    int i = blockIdx.x, b = blockIdx.y, lane = threadIdx.x;
    float4 bi = tbox[(size_t)b * TOPN + i];
    float areai = fmaxf((bi.z - bi.x) * (bi.w - bi.y), 0.0001f);
    u64* row = sup + ((size_t)b * TOPN + i) * 16;
#pragma unroll
    for (int w = 0; w < 16; ++w) {
        int col = w * 64 + lane;
        bool bit = false;
        if (col < TOPN) {
            float4 bj = tbox[(size_t)b * TOPN + col];
            float areaj = fmaxf((bj.z - bj.x) * (bj.w - bj.y), 0.0001f);
            float tlx = fmaxf(bi.x, bj.x), tly = fmaxf(bi.y, bj.y);
            float brx = fminf(bi.z, bj.z), bry = fminf(bi.w, bj.w);
            float ow = fmaxf(brx - tlx, 0.f), oh = fmaxf(bry - tly, 0.f);
            float inter = ow * oh;
            float uni = fmaxf(areai + areaj - inter, 0.0001f);
            bit = (col > i) && (inter / uni >= 0.6f);
        }
        u64 m = __ballot(bit);
        if (lane == 0) row[w] = m;
    }
}

// -------------------------------------------------------------------------
// Stage 4: greedy serial scan.  Branchless inner loop + register
// double-buffered LDS prefetch (8 rows ahead); waves 1..15 stage the next
// 128-row chunk from global into the other LDS buffer while wave 0 scans.
// -------------------------------------------------------------------------
#define CHROWS 128
#define NCHUNK 8     // 7*128 + 104 = 1000 (104 is a multiple of 8)

__global__ __launch_bounds__(1024) void finalize_kernel(
    const float* __restrict__ tscore, const float* __restrict__ tcls,
    const float4* __restrict__ tbox, const u64* __restrict__ sup,
    float* __restrict__ out)
{
    __shared__ u64 mat[2][CHROWS * 16];   // 2 x 16 KB
    __shared__ u32 validsh[TOPN];
    __shared__ u64 removed_sh[16];
    __shared__ u32 scanbuf[1024];
    int b = blockIdx.x, tid = threadIdx.x;
    int wave = tid >> 6, lane = tid & 63;

    for (int i = tid; i < TOPN; i += 1024)
        validsh[i] = (tscore[(size_t)b * TOPN + i] > 0.05f) ? 1u : 0u;

    const u64* supb = sup + (size_t)b * TOPN * 16;
    // preload chunk 0 (all threads)
    for (int idx = tid; idx < CHROWS * 16; idx += 1024)
        mat[0][idx] = supb[idx];
    __syncthreads();

    u64 my = 0;
    if (wave == 0) {
        // seed removed with ~valid: "active" == !removed_bit
#pragma unroll
        for (int w2 = 0; w2 < 16; ++w2) {
            int i = w2 * 64 + lane;
            bool v = (i < TOPN) ? (validsh[i] != 0) : false;
            u64 m = __ballot(v);
            if (lane == w2) my = ~m;
        }
    }

    for (int chunk = 0; chunk < NCHUNK; ++chunk) {
        // stage chunk+1 with waves 1..15 while wave 0 scans this chunk
        if (wave > 0 && chunk + 1 < NCHUNK) {
            int nr = (chunk + 1 == NCHUNK - 1) ? (TOPN - (NCHUNK - 1) * CHROWS) : CHROWS;
            const u64* src = supb + (size_t)(chunk + 1) * CHROWS * 16;
            u64* dst = mat[(chunk + 1) & 1];
            for (int idx = tid - 64; idx < nr * 16; idx += 960)
                dst[idx] = src[idx];
        }
        if (wave == 0) {
            int r0 = chunk * CHROWS;
            int rows = (chunk == NCHUNK - 1) ? (TOPN - r0) : CHROWS;
            int lw = lane & 15;
            const u64* M = mat[chunk & 1];
            for (int sub = 0; sub < rows; sub += 64) {
                int w2 = (r0 + sub) >> 6;
                u64 cur = __shfl(my, w2);
                int nsub = rows - sub; if (nsub > 64) nsub = 64;  // 64 or 40
                const u64* R = M + sub * 16;
                int ngrp = nsub >> 3;                             // multiples of 8
                u64 cme[8], cww[8];
#pragma unroll
                for (int g = 0; g < 8; ++g) { cme[g] = R[g*16 + lw]; cww[g] = R[g*16 + w2]; }
                for (int grp = 0; grp < ngrp; ++grp) {
                    u64 nme[8] = {0,0,0,0,0,0,0,0}, nww[8] = {0,0,0,0,0,0,0,0};
                    if (grp + 1 < ngrp) {
                        const u64* Rn = R + (grp + 1) * 128;
#pragma unroll
                        for (int g = 0; g < 8; ++g) { nme[g] = Rn[g*16 + lw]; nww[g] = Rn[g*16 + w2]; }
                    }
#pragma unroll
                    for (int g = 0; g < 8; ++g) {
                        int u = grp * 8 + g;
                        u64 bit = (cur >> u) & 1ull;
                        u64 act = bit - 1ull;     // 0 -> all-ones (active), 1 -> 0
                        cur |= cww[g] & act;
                        my  |= cme[g] & act;
                    }
#pragma unroll
                    for (int g = 0; g < 8; ++g) { cme[g] = nme[g]; cww[g] = nww[g]; }
                }
            }
        }
        __syncthreads();
    }
    if (wave == 0 && lane < 16) removed_sh[lane] = my;
    __syncthreads();

    u32 keep = 0;
    if (tid < TOPN)
        keep = (validsh[tid] && !((removed_sh[tid >> 6] >> (tid & 63)) & 1ull)) ? 1u : 0u;
    scanbuf[tid] = keep;
    __syncthreads();
    for (int off = 1; off < 1024; off <<= 1) {
        u32 add = (tid >= off) ? scanbuf[tid - off] : 0;
        __syncthreads();
        scanbuf[tid] += add;
        __syncthreads();
    }
    int rank = (int)scanbuf[tid] - 1;

    float* out_s = out;
    float* out_c = out + NBATCH * MAXOBJ;
    float* out_b = out + 2 * NBATCH * MAXOBJ;
    if (tid < MAXOBJ)     { out_s[b * MAXOBJ + tid] = -1.f; out_c[b * MAXOBJ + tid] = -1.f; }
    if (tid < MAXOBJ * 4) out_b[b * MAXOBJ * 4 + tid] = 0.f;
    __syncthreads();
    if (tid < TOPN && keep && rank < MAXOBJ) {
        size_t o = (size_t)b * TOPN + tid;
        out_s[b * MAXOBJ + rank] = tscore[o];
        out_c[b * MAXOBJ + rank] = tcls[o];
        ((float4*)out_b)[b * MAXOBJ + rank] = tbox[o];
    }
}

// -------------------------------------------------------------------------
// Workspace layout (bytes): ~10.32 MB
// -------------------------------------------------------------------------
extern "C" void kernel_launch(void* const* d_in, const int* in_sizes, int n_in,
                              void* d_out, int out_size, void* d_ws, size_t ws_size,
                              hipStream_t stream) {
    (void)in_sizes; (void)n_in; (void)out_size; (void)ws_size;
    const float* cls[5]; const float* reg[5]; const float* ctr[5];
    for (int l = 0; l < 5; ++l) {
        cls[l] = (const float*)d_in[4 * l + 0];
        reg[l] = (const float*)d_in[4 * l + 1];
        ctr[l] = (const float*)d_in[4 * l + 2];
    }
    char* w = (char*)d_ws;
    u32*    keys   = (u32*)(w + 0);
    int*    clsidx = (int*)(w + 1396736);
    float4* boxes  = (float4*)(w + 2793472);
    float*  tscore = (float*)(w + 8380416);
    float*  tcls   = (float*)(w + 8444416);
    float4* tbox   = (float4*)(w + 8508416);
    u64*    sup    = (u64*)(w + 8764416);

    decode_kernel<<<dim3((NTOT + 255) / 256, NBATCH), 256, 0, stream>>>(
        cls[0], cls[1], cls[2], cls[3], cls[4],
        reg[0], reg[1], reg[2], reg[3], reg[4],
        ctr[0], ctr[1], ctr[2], ctr[3], ctr[4],
        keys, clsidx, boxes);
    select_kernel<<<NBATCH, 1024, 0, stream>>>(keys, clsidx, boxes, tscore, tcls, tbox);
    iou_kernel<<<dim3(TOPN, NBATCH), 64, 0, stream>>>(tbox, sup);
    finalize_kernel<<<NBATCH, 1024, 0, stream>>>(tscore, tcls, tbox, sup, (float*)d_out);
}